// Round 4
// baseline (217.761 us; speedup 1.0000x reference)
//
#include <hip/hip_runtime.h>

typedef float f32x4 __attribute__((ext_vector_type(4)));
typedef short s16x8 __attribute__((ext_vector_type(8)));
typedef int   i32x4 __attribute__((ext_vector_type(4)));
typedef int   i32x2 __attribute__((ext_vector_type(2)));

namespace {
constexpr int B_ = 2, L_ = 2048, S_ = 2048, H_ = 16, E_ = 64;
constexpr int MBLK = 128;        // q rows per block (4 waves x 32)
constexpr int NT = 64;           // s-tile width
constexpr int NTILES = S_ / NT;  // 32
constexpr int KPAD = 72;         // LDS row stride (shorts)

#define SCALE2f 0.1803368801111204f /* 0.125 * log2(e) */
#define MBIAS2f -1.8033688e8f       /* -1e9 * 0.125 * log2(e): exp2 -> exactly 0 */

__device__ __forceinline__ unsigned pk2(float a, float b) {
  unsigned ua = __builtin_bit_cast(unsigned, a) + 0x8000u;
  unsigned ub = __builtin_bit_cast(unsigned, b) + 0x8000u;
  return __builtin_amdgcn_perm(ub, ua, 0x07060302u);
}
__device__ __forceinline__ short f2bs(float x) {
  return (short)((__builtin_bit_cast(unsigned, x) + 0x8000u) >> 16);
}
}  // namespace

extern "C" __global__ __launch_bounds__(256, 2)
void fattn_kernel(const float* __restrict__ Qg, const float* __restrict__ Kg,
                  const float* __restrict__ Vg, const float* __restrict__ Mg,
                  float* __restrict__ Og) {
  __shared__ __align__(16) short Ks[2][NT][KPAD];   // double-buffered K tile [s][e]
  __shared__ __align__(16) short Vt[2][E_][KPAD];   // double-buffered V^T tile [e][s]
  __shared__ __align__(16) short Ps[4][32][KPAD];   // per-wave P [q][s]

  const int tid  = threadIdx.x;
  const int wv   = tid >> 6;
  const int lane = tid & 63;
  const int qd   = lane >> 4;
  const int cl   = lane & 15;

  const int bid = blockIdx.x;
  const int qb  = bid & 15;         // 16 q-blocks share (b,h): K/V L2 reuse
  const int bh  = bid >> 4;
  const int h   = bh & (H_ - 1);
  const int b   = bh >> 4;

  const int l0 = qb * MBLK + wv * 32;

  // ---- Q fragments (B-operand of S^T = K Q^T)
  s16x8 qf[2][2];
#pragma unroll
  for (int mt = 0; mt < 2; ++mt) {
    const float* qp = Qg + ((((size_t)b * L_ + (l0 + mt * 16 + cl)) * H_ + h) << 6);
#pragma unroll
    for (int kb = 0; kb < 2; ++kb) {
      const int e0 = qd * 8 + kb * 32;
      f32x4 x = *(const f32x4*)(qp + e0);
      f32x4 y = *(const f32x4*)(qp + e0 + 4);
      i32x4 w = {(int)pk2(x[0], x[1]), (int)pk2(x[2], x[3]),
                 (int)pk2(y[0], y[1]), (int)pk2(y[2], y[3])};
      qf[mt][kb] = __builtin_bit_cast(s16x8, w);
    }
  }

  // ---- staging roles (256 threads)
  const int krow = tid >> 2;           // K: 64 rows x 4 thr x 16 floats
  const int kc0  = (tid & 3) << 4;
  const int vs   = tid & 63;           // V: lane = s
  const int ve0  = (tid >> 6) << 4;    // 4 groups x 16 e-rows

  const float* kptr = Kg + ((((size_t)b * S_ + krow) * H_ + h) << 6) + kc0;
  const float* vptr = Vg + ((((size_t)b * S_ + vs) * H_ + h) << 6) + ve0;
  const size_t tstep = (size_t)NT * H_ * E_;

  const float* mpt[2];
  mpt[0] = Mg + ((size_t)b * L_ + (l0 + cl)) * S_ + qd * 4;
  mpt[1] = Mg + ((size_t)b * L_ + (l0 + 16 + cl)) * S_ + qd * 4;

  f32x4 kr[4], vr[4];
#pragma unroll
  for (int i = 0; i < 4; ++i) {
    kr[i] = *(const f32x4*)(kptr + i * 4);
    vr[i] = *(const f32x4*)(vptr + i * 4);
  }

  const f32x4 zero4 = {0.f, 0.f, 0.f, 0.f};
  f32x4 acc[2][4];
#pragma unroll
  for (int mt = 0; mt < 2; ++mt)
#pragma unroll
    for (int et = 0; et < 4; ++et) acc[mt][et] = zero4;
  f32x4 rs4[2] = {zero4, zero4};

  // ---- stage tile 0 into buffer 0
  {
    i32x4 w0 = {(int)pk2(kr[0][0], kr[0][1]), (int)pk2(kr[0][2], kr[0][3]),
                (int)pk2(kr[1][0], kr[1][1]), (int)pk2(kr[1][2], kr[1][3])};
    i32x4 w1 = {(int)pk2(kr[2][0], kr[2][1]), (int)pk2(kr[2][2], kr[2][3]),
                (int)pk2(kr[3][0], kr[3][1]), (int)pk2(kr[3][2], kr[3][3])};
    *(i32x4*)&Ks[0][krow][kc0]     = w0;
    *(i32x4*)&Ks[0][krow][kc0 + 8] = w1;
#pragma unroll
    for (int j = 0; j < 4; ++j)
#pragma unroll
      for (int c = 0; c < 4; ++c) Vt[0][ve0 + j * 4 + c][vs] = f2bs(vr[j][c]);
  }
  // ---- load K/V for tile 1 into regs (consumed at end of tile 0)
#pragma unroll
  for (int i = 0; i < 4; ++i) {
    kr[i] = *(const f32x4*)(kptr + tstep + i * 4);
    vr[i] = *(const f32x4*)(vptr + tstep + i * 4);
  }
  // ---- mask tile 0 into regs
  f32x4 mcur[2][4];
#pragma unroll
  for (int mt = 0; mt < 2; ++mt)
#pragma unroll
    for (int nt = 0; nt < 4; ++nt) mcur[mt][nt] = *(const f32x4*)(mpt[mt] + nt * 16);

#pragma unroll 2
  for (int t = 0; t < NTILES; ++t) {
    const int cb = t & 1;
    __syncthreads();  // buf[cb] writes (end of t-1) now visible; buf[cb^1] readers done

    // ---- prefetch mask t+1 (latency hidden by this whole tile)
    f32x4 mnext[2][4];
    if (t + 1 < NTILES) {
#pragma unroll
      for (int mt = 0; mt < 2; ++mt)
#pragma unroll
        for (int nt = 0; nt < 4; ++nt)
          mnext[mt][nt] = *(const f32x4*)(mpt[mt] + (t + 1) * NT + nt * 16);
    }

    // ---- S^T = K Q^T
    f32x4 sc[4][2];
#pragma unroll
    for (int nt = 0; nt < 4; ++nt) {
      const s16x8 a0 = *(const s16x8*)&Ks[cb][nt * 16 + cl][qd * 8];
      const s16x8 a1 = *(const s16x8*)&Ks[cb][nt * 16 + cl][qd * 8 + 32];
#pragma unroll
      for (int mt = 0; mt < 2; ++mt) {
        f32x4 c = zero4;
        c = __builtin_amdgcn_mfma_f32_16x16x32_bf16(a0, qf[mt][0], c, 0, 0, 0);
        c = __builtin_amdgcn_mfma_f32_16x16x32_bf16(a1, qf[mt][1], c, 0, 0, 0);
        sc[nt][mt] = c;  // lane: q = mt*16+cl, s = nt*16 + qd*4 + r
      }
    }

    // ---- softmax numerator (mask from regs) + P -> LDS
#pragma unroll
    for (int mt = 0; mt < 2; ++mt)
#pragma unroll
      for (int nt = 0; nt < 4; ++nt) {
        f32x4 p;
#pragma unroll
        for (int r = 0; r < 4; ++r) {
          const float bias = (mcur[mt][nt][r] > 0.5f) ? 0.f : MBIAS2f;
          p[r] = __builtin_amdgcn_exp2f(__builtin_fmaf(sc[nt][mt][r], SCALE2f, bias));
        }
        rs4[mt] += p;
        i32x2 w = {(int)pk2(p[0], p[1]), (int)pk2(p[2], p[3])};
        *(i32x2*)&Ps[wv][mt * 16 + cl][nt * 16 + qd * 4] = w;
      }
    __asm__ volatile("s_waitcnt lgkmcnt(0)" ::: "memory");  // wave-private P visible

    // ---- O^T += V^T P
#pragma unroll
    for (int kb = 0; kb < 2; ++kb) {
      const s16x8 pb0 = *(const s16x8*)&Ps[wv][cl][kb * 32 + qd * 8];
      const s16x8 pb1 = *(const s16x8*)&Ps[wv][16 + cl][kb * 32 + qd * 8];
#pragma unroll
      for (int et = 0; et < 4; ++et) {
        const s16x8 av = *(const s16x8*)&Vt[cb][et * 16 + cl][kb * 32 + qd * 8];
        acc[0][et] = __builtin_amdgcn_mfma_f32_16x16x32_bf16(av, pb0, acc[0][et], 0, 0, 0);
        acc[1][et] = __builtin_amdgcn_mfma_f32_16x16x32_bf16(av, pb1, acc[1][et], 0, 0, 0);
      }
    }

    // ---- stage tile t+1 into buf[cb^1] (its last readers finished before this tile's barrier)
    if (t + 1 < NTILES) {
      i32x4 w0 = {(int)pk2(kr[0][0], kr[0][1]), (int)pk2(kr[0][2], kr[0][3]),
                  (int)pk2(kr[1][0], kr[1][1]), (int)pk2(kr[1][2], kr[1][3])};
      i32x4 w1 = {(int)pk2(kr[2][0], kr[2][1]), (int)pk2(kr[2][2], kr[2][3]),
                  (int)pk2(kr[3][0], kr[3][1]), (int)pk2(kr[3][2], kr[3][3])};
      *(i32x4*)&Ks[cb ^ 1][krow][kc0]     = w0;
      *(i32x4*)&Ks[cb ^ 1][krow][kc0 + 8] = w1;
#pragma unroll
      for (int j = 0; j < 4; ++j)
#pragma unroll
        for (int c = 0; c < 4; ++c) Vt[cb ^ 1][ve0 + j * 4 + c][vs] = f2bs(vr[j][c]);
    }
    // ---- issue global K/V loads for t+2 (full-tile latency window)
    if (t + 2 < NTILES) {
      const float* kp = kptr + (size_t)(t + 2) * tstep;
      const float* vp = vptr + (size_t)(t + 2) * tstep;
#pragma unroll
      for (int i = 0; i < 4; ++i) {
        kr[i] = *(const f32x4*)(kp + i * 4);
        vr[i] = *(const f32x4*)(vp + i * 4);
      }
    }
    // ---- rotate mask regs
    if (t + 1 < NTILES) {
#pragma unroll
      for (int mt = 0; mt < 2; ++mt)
#pragma unroll
        for (int nt = 0; nt < 4; ++nt) mcur[mt][nt] = mnext[mt][nt];
    }
  }

  // ---- epilogue: row-sum reduce + normalize + float4 stores
#pragma unroll
  for (int mt = 0; mt < 2; ++mt) {
    float v = rs4[mt][0] + rs4[mt][1] + rs4[mt][2] + rs4[mt][3];
    v += __shfl_xor(v, 16, 64);
    v += __shfl_xor(v, 32, 64);
    const float inv = 1.0f / v;
    const int l = l0 + mt * 16 + cl;
    float* op = Og + ((((size_t)b * H_ + h) * L_ + l) << 6) + qd * 4;
#pragma unroll
    for (int et = 0; et < 4; ++et) {
      f32x4 o = acc[mt][et] * inv;
      *(f32x4*)(op + et * 16) = o;
    }
  }
}

extern "C" void kernel_launch(void* const* d_in, const int* in_sizes, int n_in,
                              void* d_out, int out_size, void* d_ws, size_t ws_size,
                              hipStream_t stream) {
  const float* Q = (const float*)d_in[0];
  const float* K = (const float*)d_in[1];
  const float* V = (const float*)d_in[2];
  const float* M = (const float*)d_in[3];
  float* O = (float*)d_out;
  dim3 grid(B_ * H_ * (L_ / MBLK));  // 512 blocks, 2 per CU
  dim3 block(256);
  hipLaunchKernelGGL(fattn_kernel, grid, block, 0, stream, Q, K, V, M, O);
}

// Round 5
// 192.272 us; speedup vs baseline: 1.1326x; 1.1326x over previous
//
#include <hip/hip_runtime.h>

typedef float f32x4 __attribute__((ext_vector_type(4)));
typedef short s16x8 __attribute__((ext_vector_type(8)));
typedef int   i32x4 __attribute__((ext_vector_type(4)));
typedef int   i32x2 __attribute__((ext_vector_type(2)));

namespace {
constexpr int B_ = 2, L_ = 2048, S_ = 2048, H_ = 16, E_ = 64;
constexpr int MBLK = 128;        // q rows per block (4 waves x 32)
constexpr int NT = 64;           // s-tile width
constexpr int NTILES = S_ / NT;  // 32
constexpr int KPAD = 72;         // LDS row stride (shorts)

#define SCALE2f 0.1803368801111204f /* 0.125 * log2(e) */
#define MBIAS2f -1.8033688e8f       /* -1e9 * 0.125 * log2(e): exp2 -> exactly 0 */

__device__ __forceinline__ unsigned pk2(float a, float b) {
  unsigned ua = __builtin_bit_cast(unsigned, a) + 0x8000u;
  unsigned ub = __builtin_bit_cast(unsigned, b) + 0x8000u;
  return __builtin_amdgcn_perm(ub, ua, 0x07060302u);
}
__device__ __forceinline__ short f2bs(float x) {
  return (short)((__builtin_bit_cast(unsigned, x) + 0x8000u) >> 16);
}
}  // namespace

// ---- pre-pass: mask fp32 [B,1,L,S] -> 1 bit per element, u64 per (row, s-tile)
// Wb[((b*L + l) << 5) + t] = bits for s in [t*64, (t+1)*64)
extern "C" __global__ __launch_bounds__(256)
void maskpack_kernel(const float* __restrict__ Mg, unsigned long long* __restrict__ Wb) {
  const int w    = (int)((blockIdx.x * 256 + threadIdx.x) >> 6);  // global wave id [0,2048)
  const int lane = threadIdx.x & 63;
  const float* src = Mg + (size_t)w * 4096 + lane;   // wave covers 4096 consecutive floats
  unsigned long long* dst = Wb + (size_t)w * 64;
#pragma unroll 4
  for (int j = 0; j < 64; ++j) {
    const float m = src[j * 64];
    const unsigned long long bits = __ballot(m > 0.5f);
    if (lane == 0) dst[j] = bits;
  }
}

extern "C" __global__ __launch_bounds__(256, 2)
void fattn_kernel(const float* __restrict__ Qg, const float* __restrict__ Kg,
                  const float* __restrict__ Vg, const unsigned long long* __restrict__ Wb,
                  float* __restrict__ Og) {
  __shared__ __align__(16) short Ks[2][NT][KPAD];   // double-buffered K tile [s][e]
  __shared__ __align__(16) short Vt[2][E_][KPAD];   // double-buffered V^T tile [e][s]
  __shared__ __align__(16) short Ps[4][32][KPAD];   // per-wave P [q][s]

  const int tid  = threadIdx.x;
  const int wv   = tid >> 6;
  const int lane = tid & 63;
  const int qd   = lane >> 4;
  const int cl   = lane & 15;

  // XCD-locality swizzle: bid%8 == bh%8 -> all 16 q-blocks of one (b,h) on one XCD
  const int bid = blockIdx.x;
  const int qb  = bid >> 5;
  const int bh  = bid & 31;
  const int h   = bh & (H_ - 1);
  const int b   = bh >> 4;

  const int l0 = qb * MBLK + wv * 32;

  // ---- Q fragments (B-operand of S^T = K Q^T)
  s16x8 qf[2][2];
#pragma unroll
  for (int mt = 0; mt < 2; ++mt) {
    const float* qp = Qg + ((((size_t)b * L_ + (l0 + mt * 16 + cl)) * H_ + h) << 6);
#pragma unroll
    for (int kb = 0; kb < 2; ++kb) {
      const int e0 = qd * 8 + kb * 32;
      f32x4 x = *(const f32x4*)(qp + e0);
      f32x4 y = *(const f32x4*)(qp + e0 + 4);
      i32x4 w = {(int)pk2(x[0], x[1]), (int)pk2(x[2], x[3]),
                 (int)pk2(y[0], y[1]), (int)pk2(y[2], y[3])};
      qf[mt][kb] = __builtin_bit_cast(s16x8, w);
    }
  }

  // ---- staging roles (256 threads)
  const int krow = tid >> 2;           // K: 64 rows x 4 thr x 16 floats
  const int kc0  = (tid & 3) << 4;
  const int vs   = tid & 63;           // V: lane = s
  const int ve0  = (tid >> 6) << 4;    // 4 groups x 16 e-rows

  const float* kptr = Kg + ((((size_t)b * S_ + krow) * H_ + h) << 6) + kc0;
  const float* vptr = Vg + ((((size_t)b * S_ + vs) * H_ + h) << 6) + ve0;
  const size_t tstep = (size_t)NT * H_ * E_;

  // bit-mask row pointers (u64 per s-tile), fully L2-resident (1 MB total)
  const unsigned long long* wbp[2];
  wbp[0] = Wb + (((size_t)b * L_ + (l0 + cl)) << 5);
  wbp[1] = Wb + (((size_t)b * L_ + (l0 + 16 + cl)) << 5);

  f32x4 kr[4], vr[4];
#pragma unroll
  for (int i = 0; i < 4; ++i) {
    kr[i] = *(const f32x4*)(kptr + i * 4);
    vr[i] = *(const f32x4*)(vptr + i * 4);
  }

  const f32x4 zero4 = {0.f, 0.f, 0.f, 0.f};
  f32x4 acc[2][4];
#pragma unroll
  for (int mt = 0; mt < 2; ++mt)
#pragma unroll
    for (int et = 0; et < 4; ++et) acc[mt][et] = zero4;
  f32x4 rs4[2] = {zero4, zero4};

  // ---- stage tile 0 into buffer 0
  {
    i32x4 w0 = {(int)pk2(kr[0][0], kr[0][1]), (int)pk2(kr[0][2], kr[0][3]),
                (int)pk2(kr[1][0], kr[1][1]), (int)pk2(kr[1][2], kr[1][3])};
    i32x4 w1 = {(int)pk2(kr[2][0], kr[2][1]), (int)pk2(kr[2][2], kr[2][3]),
                (int)pk2(kr[3][0], kr[3][1]), (int)pk2(kr[3][2], kr[3][3])};
    *(i32x4*)&Ks[0][krow][kc0]     = w0;
    *(i32x4*)&Ks[0][krow][kc0 + 8] = w1;
#pragma unroll
    for (int j = 0; j < 4; ++j)
#pragma unroll
      for (int c = 0; c < 4; ++c) Vt[0][ve0 + j * 4 + c][vs] = f2bs(vr[j][c]);
  }
  // ---- load K/V for tile 1 into regs
#pragma unroll
  for (int i = 0; i < 4; ++i) {
    kr[i] = *(const f32x4*)(kptr + tstep + i * 4);
    vr[i] = *(const f32x4*)(vptr + tstep + i * 4);
  }
  // ---- mask bits tile 0
  unsigned long long mwcur[2] = {wbp[0][0], wbp[1][0]};

  for (int t = 0; t < NTILES; ++t) {
    const int cb = t & 1;
    __syncthreads();  // buf[cb] writes (end of t-1) visible; buf[cb^1] readers done

    // ---- prefetch mask bits t+1
    unsigned long long mwnext[2];
    if (t + 1 < NTILES) {
      mwnext[0] = wbp[0][t + 1];
      mwnext[1] = wbp[1][t + 1];
    }

    // ---- S^T = K Q^T
    f32x4 sc[4][2];
#pragma unroll
    for (int nt = 0; nt < 4; ++nt) {
      const s16x8 a0 = *(const s16x8*)&Ks[cb][nt * 16 + cl][qd * 8];
      const s16x8 a1 = *(const s16x8*)&Ks[cb][nt * 16 + cl][qd * 8 + 32];
#pragma unroll
      for (int mt = 0; mt < 2; ++mt) {
        f32x4 c = zero4;
        c = __builtin_amdgcn_mfma_f32_16x16x32_bf16(a0, qf[mt][0], c, 0, 0, 0);
        c = __builtin_amdgcn_mfma_f32_16x16x32_bf16(a1, qf[mt][1], c, 0, 0, 0);
        sc[nt][mt] = c;  // lane: q = mt*16+cl, s = nt*16 + qd*4 + r
      }
    }

    // ---- softmax numerator (mask from bit-register) + P -> LDS
#pragma unroll
    for (int mt = 0; mt < 2; ++mt) {
      const unsigned lo = (unsigned)mwcur[mt];
      const unsigned hi = (unsigned)(mwcur[mt] >> 32);
#pragma unroll
      for (int nt = 0; nt < 4; ++nt) {
        const unsigned sh = ((nt < 2) ? lo : hi) >> ((nt & 1) * 16 + qd * 4);
        f32x4 p;
#pragma unroll
        for (int r = 0; r < 4; ++r) {
          const float bias = (sh & (1u << r)) ? 0.f : MBIAS2f;
          p[r] = __builtin_amdgcn_exp2f(__builtin_fmaf(sc[nt][mt][r], SCALE2f, bias));
        }
        rs4[mt] += p;
        i32x2 w = {(int)pk2(p[0], p[1]), (int)pk2(p[2], p[3])};
        *(i32x2*)&Ps[wv][mt * 16 + cl][nt * 16 + qd * 4] = w;
      }
    }
    __asm__ volatile("s_waitcnt lgkmcnt(0)" ::: "memory");  // wave-private P visible

    // ---- O^T += V^T P
#pragma unroll
    for (int kb = 0; kb < 2; ++kb) {
      const s16x8 pb0 = *(const s16x8*)&Ps[wv][cl][kb * 32 + qd * 8];
      const s16x8 pb1 = *(const s16x8*)&Ps[wv][16 + cl][kb * 32 + qd * 8];
#pragma unroll
      for (int et = 0; et < 4; ++et) {
        const s16x8 av = *(const s16x8*)&Vt[cb][et * 16 + cl][kb * 32 + qd * 8];
        acc[0][et] = __builtin_amdgcn_mfma_f32_16x16x32_bf16(av, pb0, acc[0][et], 0, 0, 0);
        acc[1][et] = __builtin_amdgcn_mfma_f32_16x16x32_bf16(av, pb1, acc[1][et], 0, 0, 0);
      }
    }

    // ---- stage tile t+1 into buf[cb^1]
    if (t + 1 < NTILES) {
      i32x4 w0 = {(int)pk2(kr[0][0], kr[0][1]), (int)pk2(kr[0][2], kr[0][3]),
                  (int)pk2(kr[1][0], kr[1][1]), (int)pk2(kr[1][2], kr[1][3])};
      i32x4 w1 = {(int)pk2(kr[2][0], kr[2][1]), (int)pk2(kr[2][2], kr[2][3]),
                  (int)pk2(kr[3][0], kr[3][1]), (int)pk2(kr[3][2], kr[3][3])};
      *(i32x4*)&Ks[cb ^ 1][krow][kc0]     = w0;
      *(i32x4*)&Ks[cb ^ 1][krow][kc0 + 8] = w1;
#pragma unroll
      for (int j = 0; j < 4; ++j)
#pragma unroll
        for (int c = 0; c < 4; ++c) Vt[cb ^ 1][ve0 + j * 4 + c][vs] = f2bs(vr[j][c]);
    }
    // ---- issue global K/V loads for t+2
    if (t + 2 < NTILES) {
      const float* kp = kptr + (size_t)(t + 2) * tstep;
      const float* vp = vptr + (size_t)(t + 2) * tstep;
#pragma unroll
      for (int i = 0; i < 4; ++i) {
        kr[i] = *(const f32x4*)(kp + i * 4);
        vr[i] = *(const f32x4*)(vp + i * 4);
      }
    }
    if (t + 1 < NTILES) {
      mwcur[0] = mwnext[0];
      mwcur[1] = mwnext[1];
    }
  }

  // ---- epilogue: row-sum reduce + normalize + float4 stores
#pragma unroll
  for (int mt = 0; mt < 2; ++mt) {
    float v = rs4[mt][0] + rs4[mt][1] + rs4[mt][2] + rs4[mt][3];
    v += __shfl_xor(v, 16, 64);
    v += __shfl_xor(v, 32, 64);
    const float inv = 1.0f / v;
    const int l = l0 + mt * 16 + cl;
    float* op = Og + ((((size_t)b * H_ + h) * L_ + l) << 6) + qd * 4;
#pragma unroll
    for (int et = 0; et < 4; ++et) {
      f32x4 o = acc[mt][et] * inv;
      *(f32x4*)(op + et * 16) = o;
    }
  }
}

extern "C" void kernel_launch(void* const* d_in, const int* in_sizes, int n_in,
                              void* d_out, int out_size, void* d_ws, size_t ws_size,
                              hipStream_t stream) {
  const float* Q = (const float*)d_in[0];
  const float* K = (const float*)d_in[1];
  const float* V = (const float*)d_in[2];
  const float* M = (const float*)d_in[3];
  float* O = (float*)d_out;
  unsigned long long* Wb = (unsigned long long*)d_ws;  // needs 2*2048*32*8 = 1 MiB

  hipLaunchKernelGGL(maskpack_kernel, dim3(512), dim3(256), 0, stream, M, Wb);
  hipLaunchKernelGGL(fattn_kernel, dim3(B_ * H_ * (L_ / MBLK)), dim3(256), 0, stream,
                     Q, K, V, Wb, O);
}

// Round 7
// 178.209 us; speedup vs baseline: 1.2219x; 1.0789x over previous
//
#include <hip/hip_runtime.h>

typedef float    f32x4 __attribute__((ext_vector_type(4)));
typedef _Float16 f16x2 __attribute__((ext_vector_type(2)));
typedef _Float16 f16x4 __attribute__((ext_vector_type(4)));
typedef _Float16 f16x8 __attribute__((ext_vector_type(8)));
typedef int      i32x4 __attribute__((ext_vector_type(4)));

namespace {
constexpr int B_ = 2, L_ = 2048, S_ = 2048, H_ = 16, E_ = 64;
constexpr int MBLK = 128;        // q rows per block (4 waves x 32)
constexpr int NT = 64;           // s-tile width
constexpr int NTILES = S_ / NT;  // 32
constexpr int KPAD = 72;         // LDS row stride (halves): 36 dw, 16B-aligned rows, 2-way banks

#define SCALE2f 0.1803368801111204f /* 0.125 * log2(e) */
#define MBIAS2f -1.8033688e8f       /* -1e9 * 0.125 * log2(e): exp2 -> exactly 0 */

__device__ __forceinline__ f16x2 cvt2(float a, float b) {  // 2x f32 -> f16x2 (1 instr)
  return __builtin_bit_cast(f16x2, __builtin_amdgcn_cvt_pkrtz(a, b));
}
__device__ __forceinline__ int pkh(float a, float b) {
  return __builtin_bit_cast(int, __builtin_amdgcn_cvt_pkrtz(a, b));
}
union H8 { f16x8 v; i32x4 i; };
union H4 { f16x4 v; f16x2 h[2]; };
}  // namespace

// ---- pre-pass: mask fp32 [B,1,L,S] -> 1 bit/element, u64 per (row, s-tile)
extern "C" __global__ __launch_bounds__(256)
void maskpack_kernel(const float* __restrict__ Mg, unsigned long long* __restrict__ Wb) {
  const int w    = (int)((blockIdx.x * 256 + threadIdx.x) >> 6);  // row id [0, B*L)
  const int lane = threadIdx.x & 63;
  const float* src = Mg + (size_t)w * 2048 + lane;
  unsigned long long* dst = Wb + (size_t)w * 32;
#pragma unroll 8
  for (int j = 0; j < 32; ++j) {
    const unsigned long long bits = __ballot(src[j * 64] > 0.5f);
    if (lane == 0) dst[j] = bits;
  }
}

extern "C" __global__ __launch_bounds__(256, 2)
void fattn_kernel(const float* __restrict__ Qg, const float* __restrict__ Kg,
                  const float* __restrict__ Vg, const unsigned long long* __restrict__ Wb,
                  float* __restrict__ Og) {
  __shared__ __align__(16) _Float16 Ks[2][NT][KPAD];  // K tile [s][e], double-buffered
  __shared__ __align__(16) _Float16 Vt[2][E_][KPAD];  // V^T tile [e][s], double-buffered

  const int tid  = threadIdx.x;
  const int wv   = tid >> 6;
  const int lane = tid & 63;
  const int qd   = lane >> 4;
  const int cl   = lane & 15;

  // XCD-locality: bid%8 == bh%8 -> all 16 q-blocks of one (b,h) on one XCD
  const int bid = blockIdx.x;
  const int qb  = bid >> 5;
  const int bh  = bid & 31;
  const int h   = bh & (H_ - 1);
  const int b   = bh >> 4;

  const int l0 = qb * MBLK + wv * 32;

  // ---- Q fragments (B-operand of S^T = K Q^T), f16
  f16x8 qf[2][2];
#pragma unroll
  for (int mt = 0; mt < 2; ++mt) {
    const float* qp = Qg + ((((size_t)b * L_ + (l0 + mt * 16 + cl)) * H_ + h) << 6);
#pragma unroll
    for (int kb = 0; kb < 2; ++kb) {
      const int e0 = qd * 8 + kb * 32;
      f32x4 x = *(const f32x4*)(qp + e0);
      f32x4 y = *(const f32x4*)(qp + e0 + 4);
      H8 u;
      u.i = (i32x4){pkh(x[0], x[1]), pkh(x[2], x[3]), pkh(y[0], y[1]), pkh(y[2], y[3])};
      qf[mt][kb] = u.v;
    }
  }

  // ---- staging roles (256 threads)
  const int krow = tid >> 2;           // K: 64 rows x 4 thr x 16 floats
  const int kc0  = (tid & 3) << 4;
  const int vcol = tid & 31;           // V: s-pair index (s = 2*vcol, 2*vcol+1)
  const int ve0  = (tid >> 5) << 3;    // 8 e-rows per thread group

  const float* kptr  = Kg + ((((size_t)b * S_ + krow) * H_ + h) << 6) + kc0;
  const float* vptrA = Vg + ((((size_t)b * S_ + 2 * vcol) * H_ + h) << 6) + ve0;
  const float* vptrB = vptrA + (H_ << 6);  // next s row
  const size_t tstep = (size_t)NT * H_ * E_;

  const unsigned long long* wbp[2];
  wbp[0] = Wb + (((size_t)b * L_ + (l0 + cl)) << 5);
  wbp[1] = Wb + (((size_t)b * L_ + (l0 + 16 + cl)) << 5);

  f32x4 kr[4], va[2], vb[2];
#pragma unroll
  for (int i = 0; i < 4; ++i) kr[i] = *(const f32x4*)(kptr + i * 4);
  va[0] = *(const f32x4*)(vptrA + 0); va[1] = *(const f32x4*)(vptrA + 4);
  vb[0] = *(const f32x4*)(vptrB + 0); vb[1] = *(const f32x4*)(vptrB + 4);

  const f32x4 zero4 = {0.f, 0.f, 0.f, 0.f};
  f32x4 acc[2][4];  // D[m=q][n=e]: q = mt*16 + qd*4 + r, e = et*16 + cl
#pragma unroll
  for (int mt = 0; mt < 2; ++mt)
#pragma unroll
    for (int et = 0; et < 4; ++et) acc[mt][et] = zero4;
  f32x4 rs4[2] = {zero4, zero4};

  // ---- stage tile 0 into buffer 0
  {
    i32x4 w0 = {pkh(kr[0][0], kr[0][1]), pkh(kr[0][2], kr[0][3]),
                pkh(kr[1][0], kr[1][1]), pkh(kr[1][2], kr[1][3])};
    i32x4 w1 = {pkh(kr[2][0], kr[2][1]), pkh(kr[2][2], kr[2][3]),
                pkh(kr[3][0], kr[3][1]), pkh(kr[3][2], kr[3][3])};
    *(i32x4*)&Ks[0][krow][kc0]     = w0;
    *(i32x4*)&Ks[0][krow][kc0 + 8] = w1;
#pragma unroll
    for (int j = 0; j < 4; ++j) {
      *(f16x2*)&Vt[0][ve0 + j][2 * vcol]     = cvt2(va[0][j], vb[0][j]);
      *(f16x2*)&Vt[0][ve0 + 4 + j][2 * vcol] = cvt2(va[1][j], vb[1][j]);
    }
  }
  // ---- load K/V for tile 1 into regs
#pragma unroll
  for (int i = 0; i < 4; ++i) kr[i] = *(const f32x4*)(kptr + tstep + i * 4);
  va[0] = *(const f32x4*)(vptrA + tstep + 0); va[1] = *(const f32x4*)(vptrA + tstep + 4);
  vb[0] = *(const f32x4*)(vptrB + tstep + 0); vb[1] = *(const f32x4*)(vptrB + tstep + 4);

  unsigned long long mwcur[2] = {wbp[0][0], wbp[1][0]};

  for (int t = 0; t < NTILES; ++t) {
    const int cb = t & 1;
    __syncthreads();  // buf[cb] staged; buf[cb^1] readers (tile t-1) done

    unsigned long long mwnext0 = 0, mwnext1 = 0;
    if (t + 1 < NTILES) { mwnext0 = wbp[0][t + 1]; mwnext1 = wbp[1][t + 1]; }

    // ---- S^T = K Q^T  (A: Ks rows b128; B: Q regs). C: q=mt*16+cl, s=nt*16+qd*4+r
    f32x4 sc[4][2];
#pragma unroll
    for (int nt = 0; nt < 4; ++nt) {
      const f16x8 a0 = *(const f16x8*)&Ks[cb][nt * 16 + cl][qd * 8];
      const f16x8 a1 = *(const f16x8*)&Ks[cb][nt * 16 + cl][qd * 8 + 32];
#pragma unroll
      for (int mt = 0; mt < 2; ++mt) {
        f32x4 c = zero4;
        c = __builtin_amdgcn_mfma_f32_16x16x32_f16(a0, qf[mt][0], c, 0, 0, 0);
        c = __builtin_amdgcn_mfma_f32_16x16x32_f16(a1, qf[mt][1], c, 0, 0, 0);
        sc[nt][mt] = c;
      }
    }

    // ---- stage tile t+1 into buf[cb^1] (overlaps softmax/PV below)
    if (t + 1 < NTILES) {
      i32x4 w0 = {pkh(kr[0][0], kr[0][1]), pkh(kr[0][2], kr[0][3]),
                  pkh(kr[1][0], kr[1][1]), pkh(kr[1][2], kr[1][3])};
      i32x4 w1 = {pkh(kr[2][0], kr[2][1]), pkh(kr[2][2], kr[2][3]),
                  pkh(kr[3][0], kr[3][1]), pkh(kr[3][2], kr[3][3])};
      *(i32x4*)&Ks[cb ^ 1][krow][kc0]     = w0;
      *(i32x4*)&Ks[cb ^ 1][krow][kc0 + 8] = w1;
#pragma unroll
      for (int j = 0; j < 4; ++j) {
        *(f16x2*)&Vt[cb ^ 1][ve0 + j][2 * vcol]     = cvt2(va[0][j], vb[0][j]);
        *(f16x2*)&Vt[cb ^ 1][ve0 + 4 + j][2 * vcol] = cvt2(va[1][j], vb[1][j]);
      }
    }

    // ---- softmax numerator; P stays in REGISTERS as PV A-frags
    // (16x16x16 A-layout m=cl, k=qd*4+j == QK C-layout q=cl, s=qd*4+r)
    f16x4 pa[2][4];
    if (mwcur[0] == ~0ull && mwcur[1] == ~0ull) {  // all-attend fast path
#pragma unroll
      for (int mt = 0; mt < 2; ++mt)
#pragma unroll
        for (int nt = 0; nt < 4; ++nt) {
          f32x4 p;
#pragma unroll
          for (int r = 0; r < 4; ++r)
            p[r] = __builtin_amdgcn_exp2f(sc[nt][mt][r] * SCALE2f);
          rs4[mt] += p;
          H4 u;
          u.h[0] = cvt2(p[0], p[1]);
          u.h[1] = cvt2(p[2], p[3]);
          pa[mt][nt] = u.v;
        }
    } else {
#pragma unroll
      for (int mt = 0; mt < 2; ++mt) {
        const unsigned lo = (unsigned)mwcur[mt];
        const unsigned hi = (unsigned)(mwcur[mt] >> 32);
#pragma unroll
        for (int nt = 0; nt < 4; ++nt) {
          const unsigned sh = ((nt < 2) ? lo : hi) >> ((nt & 1) * 16 + qd * 4);
          f32x4 p;
#pragma unroll
          for (int r = 0; r < 4; ++r) {
            const float bias = (sh & (1u << r)) ? 0.f : MBIAS2f;
            p[r] = __builtin_amdgcn_exp2f(__builtin_fmaf(sc[nt][mt][r], SCALE2f, bias));
          }
          rs4[mt] += p;
          H4 u;
          u.h[0] = cvt2(p[0], p[1]);
          u.h[1] = cvt2(p[2], p[3]);
          pa[mt][nt] = u.v;
        }
      }
    }

    // ---- O += P V  (A: P regs; B: Vt rows b64). No LDS round-trip for P.
#pragma unroll
    for (int nt = 0; nt < 4; ++nt)
#pragma unroll
      for (int et = 0; et < 4; ++et) {
        const f16x4 bv = *(const f16x4*)&Vt[cb][et * 16 + cl][nt * 16 + qd * 4];
        acc[0][et] = __builtin_amdgcn_mfma_f32_16x16x16f16(pa[0][nt], bv, acc[0][et], 0, 0, 0);
        acc[1][et] = __builtin_amdgcn_mfma_f32_16x16x16f16(pa[1][nt], bv, acc[1][et], 0, 0, 0);
      }

    // ---- issue global K/V loads for t+2
    if (t + 2 < NTILES) {
      const float* kp = kptr + (size_t)(t + 2) * tstep;
      const float* vpA = vptrA + (size_t)(t + 2) * tstep;
      const float* vpB = vptrB + (size_t)(t + 2) * tstep;
#pragma unroll
      for (int i = 0; i < 4; ++i) kr[i] = *(const f32x4*)(kp + i * 4);
      va[0] = *(const f32x4*)(vpA + 0); va[1] = *(const f32x4*)(vpA + 4);
      vb[0] = *(const f32x4*)(vpB + 0); vb[1] = *(const f32x4*)(vpB + 4);
    }
    mwcur[0] = mwnext0;
    mwcur[1] = mwnext1;
  }

  // ---- epilogue: row-sum reduce, broadcast inv per q-row, store
#pragma unroll
  for (int mt = 0; mt < 2; ++mt) {
    float v = rs4[mt][0] + rs4[mt][1] + rs4[mt][2] + rs4[mt][3];
    v += __shfl_xor(v, 16, 64);
    v += __shfl_xor(v, 32, 64);  // every lane: sum for q = mt*16 + cl
#pragma unroll
    for (int r = 0; r < 4; ++r) {
      const float invq = 1.0f / __shfl(v, qd * 4 + r, 64);  // sum for q = mt*16+qd*4+r
      const int l = l0 + mt * 16 + qd * 4 + r;
      float* op = Og + ((((size_t)b * H_ + h) * L_ + l) << 6) + cl;
#pragma unroll
      for (int et = 0; et < 4; ++et) op[et * 16] = acc[mt][et][r] * invq;
    }
  }
}

extern "C" void kernel_launch(void* const* d_in, const int* in_sizes, int n_in,
                              void* d_out, int out_size, void* d_ws, size_t ws_size,
                              hipStream_t stream) {
  const float* Q = (const float*)d_in[0];
  const float* K = (const float*)d_in[1];
  const float* V = (const float*)d_in[2];
  const float* M = (const float*)d_in[3];
  float* O = (float*)d_out;
  unsigned long long* Wb = (unsigned long long*)d_ws;  // 2*2048*32*8 = 1 MiB

  hipLaunchKernelGGL(maskpack_kernel, dim3(B_ * L_ / 4), dim3(256), 0, stream, M, Wb);
  hipLaunchKernelGGL(fattn_kernel, dim3(B_ * H_ * (L_ / MBLK)), dim3(256), 0, stream,
                     Q, K, V, Wb, O);
}